// Round 6
// baseline (2382.971 us; speedup 1.0000x reference)
//
#include <hip/hip_runtime.h>
#include <hip/hip_bf16.h>
#include <hip/hip_cooperative_groups.h>

namespace cg = cooperative_groups;

#define BB 128
#define NN 4096
#define DD 64
#define SS 8
#define HH 128

typedef __attribute__((ext_vector_type(8))) short short8;
typedef __attribute__((ext_vector_type(4))) short short4v;
typedef __attribute__((ext_vector_type(4))) float f32x4;

__device__ __forceinline__ float warp_red_sum(float v) {
    #pragma unroll
    for (int off = 32; off; off >>= 1) v += __shfl_xor(v, off);
    return v;
}

__device__ __forceinline__ float bcastlane(float v, int l) {
    return __int_as_float(__builtin_amdgcn_readlane(__float_as_int(v), l));
}

__device__ __forceinline__ unsigned short bfu(float f) {
    __hip_bfloat16 h = __float2bfloat16(f);
    return *(unsigned short*)&h;
}

__device__ __forceinline__ unsigned pk2(float a, float b) {
    return (unsigned)bfu(a) | ((unsigned)bfu(b) << 16);
}

// hardware transpose read, CONTRIBUTE semantics (verified vs learn_hip m162):
// within a 16-lane group, lane k's 8 bytes at its own address supply row-major
// elements [4k,4k+4) of a 4x16 bf16 matrix; receiver lane l gets column (l&15).
__device__ __forceinline__ short4v ds_tr16(unsigned off) {
    short4v r;
    asm volatile("ds_read_b64_tr_b16 %0, %1" : "=v"(r) : "v"(off));
    return r;
}

// ================= shared device bodies =================

// streaming LN of 128 tokens starting at tok0 (256 threads)
__device__ __forceinline__ void ln_block(
    const float* __restrict__ inp, const float* __restrict__ niw,
    const float* __restrict__ nib, unsigned short* __restrict__ xb,
    int tok0, int tid)
{
    const int lane = tid & 63, widx = tid >> 6;
    const int t8 = lane >> 3, d8 = lane & 7;
    const float4 wn0 = *(const float4*)&niw[d8 * 8];
    const float4 wn1 = *(const float4*)&niw[d8 * 8 + 4];
    const float4 bn0 = *(const float4*)&nib[d8 * 8];
    const float4 bn1 = *(const float4*)&nib[d8 * 8 + 4];
    #pragma unroll
    for (int it = 0; it < 4; ++it) {
        const int m = widx * 32 + it * 8 + t8;
        const float* rowp = inp + (size_t)(tok0 + m) * 64 + d8 * 8;
        float4 a = *(const float4*)rowp;
        float4 c = *(const float4*)(rowp + 4);
        float s1 = (a.x + a.y + a.z + a.w) + (c.x + c.y + c.z + c.w);
        float s2 = fmaf(a.x, a.x, fmaf(a.y, a.y, fmaf(a.z, a.z, a.w * a.w)));
        s2 = fmaf(c.x, c.x, fmaf(c.y, c.y, fmaf(c.z, c.z, fmaf(c.w, c.w, s2))));
        #pragma unroll
        for (int o = 1; o < 8; o <<= 1) { s1 += __shfl_xor(s1, o); s2 += __shfl_xor(s2, o); }
        float mean = s1 * (1.0f / 64.0f);
        float var = s2 * (1.0f / 64.0f) - mean * mean;
        float rstd = rsqrtf(var + 1e-5f);
        float y[8];
        y[0] = (a.x - mean) * rstd * wn0.x + bn0.x;
        y[1] = (a.y - mean) * rstd * wn0.y + bn0.y;
        y[2] = (a.z - mean) * rstd * wn0.z + bn0.z;
        y[3] = (a.w - mean) * rstd * wn0.w + bn0.w;
        y[4] = (c.x - mean) * rstd * wn1.x + bn1.x;
        y[5] = (c.y - mean) * rstd * wn1.y + bn1.y;
        y[6] = (c.z - mean) * rstd * wn1.z + bn1.z;
        y[7] = (c.w - mean) * rstd * wn1.w + bn1.w;
        uint4 o4;
        o4.x = pk2(y[0], y[1]); o4.y = pk2(y[2], y[3]);
        o4.z = pk2(y[4], y[5]); o4.w = pk2(y[6], y[7]);
        *(uint4*)&xb[(size_t)(tok0 + m) * 64 + d8 * 8] = o4;
    }
}

// GRU + MLP + next-q' for one row (64 lanes), given reduced numer element nx and denom dt
__device__ __forceinline__ void gru_core(
    float nx, float dt, int row, int lane,
    const float* __restrict__ vwT, const float* __restrict__ wihT,
    const float* __restrict__ whhT, const float* __restrict__ w1T,
    const float* __restrict__ w2T, const float* __restrict__ bih,
    const float* __restrict__ bhh, const float* __restrict__ nrw,
    const float* __restrict__ nrb, const float* __restrict__ b2,
    const float* __restrict__ qwT, const float* __restrict__ k_w,
    const float* __restrict__ nsw, const float* __restrict__ nsb,
    const float* __restrict__ slotsIn, float* __restrict__ slotsOut,
    unsigned short* __restrict__ qb)
{
    float xp = 0.f;
    #pragma unroll 8
    for (int i = 0; i < 64; ++i) xp = fmaf(bcastlane(nx, i), vwT[i * 64 + lane], xp);
    float x = xp / dt;
    float h = slotsIn[row * 64 + lane];
    float air = 0, aiz = 0, ain = 0, ahr = 0, ahz = 0, ahn = 0;
    #pragma unroll 8
    for (int i = 0; i < 64; ++i) {
        float xi = bcastlane(x, i), hi = bcastlane(h, i);
        const float* wi = wihT + i * 192;
        const float* wh = whhT + i * 192;
        air = fmaf(xi, wi[lane], air);
        aiz = fmaf(xi, wi[64 + lane], aiz);
        ain = fmaf(xi, wi[128 + lane], ain);
        ahr = fmaf(hi, wh[lane], ahr);
        ahz = fmaf(hi, wh[64 + lane], ahz);
        ahn = fmaf(hi, wh[128 + lane], ahn);
    }
    air += bih[lane]; aiz += bih[64 + lane]; ain += bih[128 + lane];
    ahr += bhh[lane]; ahz += bhh[64 + lane]; ahn += bhh[128 + lane];
    float r = 1.f / (1.f + __expf(-(air + ahr)));
    float z = 1.f / (1.f + __expf(-(aiz + ahz)));
    float n = tanhf(ain + r * ahn);
    float hn = (1.f - z) * n + z * h;
    float m = warp_red_sum(hn) * (1.0f / 64.0f);
    float dx = hn - m;
    float var = warp_red_sum(dx * dx) * (1.0f / 64.0f);
    float u = dx * rsqrtf(var + 1e-5f) * nrw[lane] + nrb[lane];
    float o0 = 0.f, o1 = 0.f;
    #pragma unroll 8
    for (int i = 0; i < 64; ++i) {
        float ui = bcastlane(u, i);
        const float* w1r = w1T + i * 128;
        o0 = fmaf(ui, w1r[lane], o0);
        o1 = fmaf(ui, w1r[64 + lane], o1);
    }
    o0 = fmaxf(o0, 0.f); o1 = fmaxf(o1, 0.f);
    float y = 0.f;
    #pragma unroll 8
    for (int j = 0; j < 64; ++j) y = fmaf(bcastlane(o0, j), w2T[j * 64 + lane], y);
    #pragma unroll 8
    for (int j = 0; j < 64; ++j) y = fmaf(bcastlane(o1, j), w2T[(64 + j) * 64 + lane], y);
    y += b2[lane];
    float out = hn + y;
    slotsOut[row * 64 + lane] = out;
    float m2 = warp_red_sum(out) * (1.0f / 64.0f);
    float dx2 = out - m2;
    float var2 = warp_red_sum(dx2 * dx2) * (1.0f / 64.0f);
    float u2 = dx2 * rsqrtf(var2 + 1e-5f) * nsw[lane] + nsb[lane];
    float q = 0.f;
    #pragma unroll 8
    for (int i = 0; i < 64; ++i) q = fmaf(bcastlane(u2, i), qwT[i * 64 + lane], q);
    float qp = 0.f;
    #pragma unroll 8
    for (int o = 0; o < 64; ++o) qp = fmaf(bcastlane(q, o), k_w[o * 64 + lane], qp);
    qb[row * 64 + lane] = bfu(qp * 0.125f);
}

// one attention step for one (bs, xblk) 512-token block; writes per-block partials
__device__ __forceinline__ void attn_step_coop(
    const __hip_bfloat16* __restrict__ xb, const unsigned short* __restrict__ qb,
    float* __restrict__ numerP, float* __restrict__ denomP, float* __restrict__ wout,
    unsigned short* smem, int bs, int xblk, int tid, int lane, int widx,
    int quad, int l16)
{
    unsigned short* Qs = smem;                          // [16][72]
    unsigned short* wls = smem + 1152 + widx * 640;     // [16][40] per wave
    unsigned short* Xw  = smem + 3712 + widx * 2048;    // [4][32][16] per wave
    const int twave0 = xblk * 512 + widx * 128;

    short8 bkA[2][2], bkB[2][2];
    #pragma unroll
    for (int t4h = 0; t4h < 2; ++t4h) {
        const size_t xrow = ((size_t)bs * NN + twave0 + t4h * 16 + l16) * 64;
        bkA[t4h][0] = *(const short8*)&xb[xrow + quad * 8];
        bkA[t4h][1] = *(const short8*)&xb[xrow + 32 + quad * 8];
    }

    for (int t = tid; t < 1024; t += 256) {
        int s = t >> 6, dd = t & 63;
        Qs[s * 72 + dd] = (s < 8) ? qb[bs * 512 + t] : (unsigned short)0;
    }
    for (int t = lane; t < 320; t += 64) wls[320 + t] = 0;
    __syncthreads();

    short8 aq0 = *(const short8*)&Qs[l16 * 72 + quad * 8];
    short8 aq1 = *(const short8*)&Qs[l16 * 72 + 32 + quad * 8];

    f32x4 accv[4];
    #pragma unroll
    for (int nt = 0; nt < 4; ++nt) accv[nt] = (f32x4){0.f, 0.f, 0.f, 0.f};
    float dacc[4] = {0.f, 0.f, 0.f, 0.f};

    unsigned short* xw0 = Xw + (quad >> 1) * 512 + l16 * 16 + (quad & 1) * 8;
    const unsigned xtr = (unsigned)(size_t)Xw
                       + (unsigned)((quad * 8 + (l16 >> 2)) * 32 + (l16 & 3) * 8);

    auto PROC = [&](short8 (&cur)[2][2], short8 (&nxt)[2][2], int hg, bool pf) {
        const int t0g = twave0 + hg * 32;
        if (pf) {
            #pragma unroll
            for (int t4h = 0; t4h < 2; ++t4h) {
                const size_t xrow = ((size_t)bs * NN + t0g + 32 + t4h * 16 + l16) * 64;
                nxt[t4h][0] = *(const short8*)&xb[xrow + quad * 8];
                nxt[t4h][1] = *(const short8*)&xb[xrow + 32 + quad * 8];
            }
        }
        #pragma unroll
        for (int t4h = 0; t4h < 2; ++t4h) {
            const int tok = t0g + t4h * 16 + l16;
            short8 bk0 = cur[t4h][0];
            short8 bk1 = cur[t4h][1];
            *(short8*)(xw0 + t4h * 256) = bk0;
            *(short8*)(xw0 + t4h * 256 + 1024) = bk1;
            f32x4 lg = (f32x4){0.f, 0.f, 0.f, 0.f};
            lg = __builtin_amdgcn_mfma_f32_16x16x32_bf16(aq0, bk0, lg, 0, 0, 0);
            lg = __builtin_amdgcn_mfma_f32_16x16x32_bf16(aq1, bk1, lg, 0, 0, 0);
            float e[4];
            #pragma unroll
            for (int r = 0; r < 4; ++r) e[r] = __expf(lg[r]);
            float s4 = (e[0] + e[1]) + (e[2] + e[3]);
            float stot = s4 + __shfl_xor(s4, 16);
            float rs = __builtin_amdgcn_rcpf(stot);
            float wv[4];
            #pragma unroll
            for (int r = 0; r < 4; ++r) { wv[r] = fmaf(e[r], rs, 1e-8f); dacc[r] += wv[r]; }
            if (quad < 2) {
                #pragma unroll
                for (int r = 0; r < 4; ++r)
                    wls[(quad * 4 + r) * 40 + t4h * 16 + l16] = bfu(wv[r]);
                if (wout)
                    *(float4*)&wout[((size_t)bs * NN + tok) * 8 + quad * 4] =
                        make_float4(wv[0], wv[1], wv[2], wv[3]);
            }
        }
        asm volatile("" ::: "memory");
        short8 aw = *(const short8*)&wls[l16 * 40 + quad * 8];
        short4v rlo[4], rhi[4];
        #pragma unroll
        for (int nt = 0; nt < 4; ++nt) {
            rlo[nt] = ds_tr16(xtr + nt * 1024);
            rhi[nt] = ds_tr16(xtr + nt * 1024 + 128);
        }
        asm volatile("s_waitcnt lgkmcnt(0)");
        __builtin_amdgcn_sched_barrier(0);
        #pragma unroll
        for (int nt = 0; nt < 4; ++nt) {
            short8 bv = __builtin_shufflevector(rlo[nt], rhi[nt], 0, 1, 2, 3, 4, 5, 6, 7);
            accv[nt] = __builtin_amdgcn_mfma_f32_16x16x32_bf16(aw, bv, accv[nt], 0, 0, 0);
        }
    };

    PROC(bkA, bkB, 0, true);
    PROC(bkB, bkA, 1, true);
    PROC(bkA, bkB, 2, true);
    PROC(bkB, bkA, 3, false);

    #pragma unroll
    for (int r = 0; r < 4; ++r) {
        dacc[r] += __shfl_xor(dacc[r], 1);
        dacc[r] += __shfl_xor(dacc[r], 2);
        dacc[r] += __shfl_xor(dacc[r], 4);
        dacc[r] += __shfl_xor(dacc[r], 8);
    }
    __syncthreads();
    float* red = (float*)smem;
    float* dred = red + 2048;
    if (quad < 2) {
        #pragma unroll
        for (int nt = 0; nt < 4; ++nt)
            #pragma unroll
            for (int r = 0; r < 4; ++r)
                red[widx * 512 + (quad * 4 + r) * 64 + nt * 16 + l16] = accv[nt][r];
        if (l16 == 0) {
            #pragma unroll
            for (int r = 0; r < 4; ++r) dred[widx * 8 + quad * 4 + r] = dacc[r];
        }
    }
    __syncthreads();
    float* np = numerP + ((size_t)bs * 8 + xblk) * 512;
    for (int e = tid; e < 512; e += 256)
        np[e] = red[e] + red[512 + e] + red[1024 + e] + red[1536 + e];
    if (tid < 8)
        denomP[((size_t)bs * 8 + xblk) * 8 + tid] =
            dred[tid] + dred[8 + tid] + dred[16 + tid] + dred[24 + tid];
}

// ================= mega cooperative kernel =================

struct MegaArgs {
    const float *inputs, *eps, *mu, *lv, *k_w, *v_w, *q_w;
    const float *niw, *nib, *nsw, *nsb, *nrw, *nrb;
    const float *wih, *whh, *bih, *bhh, *w1, *w2, *b2;
    unsigned short *xb, *qb;
    float *slotsA, *slotsB, *numerP, *denomP, *denomF;
    float *vwT, *qwT, *wihT, *whhT, *w1T, *w2T;
    float *out_slots, *out_w;
};

__global__ __launch_bounds__(256, 4) void mega_kernel(MegaArgs a)
{
    cg::grid_group grid = cg::this_grid();
    __shared__ unsigned short smem[11904];
    const int bid = blockIdx.x;
    const int tid = threadIdx.x, lane = tid & 63, widx = tid >> 6;
    const int quad = lane >> 4, l16 = lane & 15;

    // -------- phase 0a: weight transposes (blocks 0..63) --------
    if (bid < 64) {
        int i0 = bid * 256 + tid, nthr = 16384;
        for (int t = i0; t < 4096; t += nthr) {
            int i = t >> 6, o = t & 63;
            a.vwT[t] = a.v_w[o * 64 + i];
            a.qwT[t] = a.q_w[o * 64 + i];
        }
        for (int t = i0; t < 12288; t += nthr) {
            int r = t / 192, c = t % 192;
            a.wihT[t] = a.wih[c * 64 + r];
            a.whhT[t] = a.whh[c * 64 + r];
        }
        for (int t = i0; t < 8192; t += nthr) {
            int r = t >> 7, c = t & 127;
            a.w1T[t] = a.w1[c * 64 + r];
        }
        for (int t = i0; t < 8192; t += nthr) {
            int r = t >> 6, c = t & 63;
            a.w2T[t] = a.w2[c * 128 + r];
        }
    }
    // -------- phase 0b: streaming LN (all blocks, 4 chunks of 128 tokens) --------
    for (int c = 0; c < 4; ++c)
        ln_block(a.inputs, a.niw, a.nib, a.xb, (bid * 4 + c) * 128, tid);
    // -------- phase 0c: slot init + first q' (one wave per block; direct q_w reads) --------
    if (widx == (bid & 3)) {
        const int row = bid;
        const int idx = row * 64 + lane;
        float s0 = a.mu[lane] + __expf(0.5f * a.lv[lane]) * a.eps[idx];
        a.slotsA[idx] = s0;
        float m = warp_red_sum(s0) * (1.0f / 64.0f);
        float dx = s0 - m;
        float var = warp_red_sum(dx * dx) * (1.0f / 64.0f);
        float xln = dx * rsqrtf(var + 1e-5f) * a.nsw[lane] + a.nsb[lane];
        float q = 0.f;
        #pragma unroll 8
        for (int i = 0; i < 64; ++i) q = fmaf(bcastlane(xln, i), a.q_w[lane * 64 + i], q);
        float qp = 0.f;
        #pragma unroll 8
        for (int o = 0; o < 64; ++o) qp = fmaf(bcastlane(q, o), a.k_w[o * 64 + lane], qp);
        a.qb[idx] = bfu(qp * 0.125f);
    }
    __threadfence();
    grid.sync();

    const int xblk = bid & 7, bs = bid >> 3;
    for (int step = 0; step < 4; ++step) {
        const bool last = (step == 3);
        attn_step_coop((const __hip_bfloat16*)a.xb, a.qb, a.numerP, a.denomP,
                       last ? a.out_w : nullptr, smem, bs, xblk,
                       tid, lane, widx, quad, l16);
        __threadfence();
        grid.sync();
        if (widx == (bid & 3)) {
            const int row = bid, bb = row >> 3, ss = row & 7;
            float nx = 0.f;
            #pragma unroll
            for (int xx = 0; xx < 8; ++xx)
                nx += a.numerP[((size_t)bb * 8 + xx) * 512 + ss * 64 + lane];
            float dt = 0.f;
            #pragma unroll
            for (int xx = 0; xx < 8; ++xx)
                dt += a.denomP[((size_t)bb * 8 + xx) * 8 + ss];
            if (lane == 0) a.denomF[row] = dt;
            const float* sIn = (step & 1) ? a.slotsB : a.slotsA;
            float* sOut = last ? a.out_slots : ((step & 1) ? a.slotsA : a.slotsB);
            gru_core(nx, dt, row, lane, a.vwT, a.wihT, a.whhT, a.w1T, a.w2T,
                     a.bih, a.bhh, a.nrw, a.nrb, a.b2, a.qwT, a.k_w, a.nsw, a.nsb,
                     sIn, sOut, a.qb);
        }
        __threadfence();
        grid.sync();
    }
    // -------- final: renorm w over tokens --------
    for (int it = 0; it < 4; ++it) {
        size_t i4 = (size_t)bid * 1024 + it * 256 + tid;
        size_t b = i4 >> 13;
        int half = (int)(i4 & 1);
        float4 v = ((float4*)a.out_w)[i4];
        const float4 dv = *(const float4*)&a.denomF[b * 8 + half * 4];
        v.x /= dv.x; v.y /= dv.y; v.z /= dv.z; v.w /= dv.w;
        ((float4*)a.out_w)[i4] = v;
    }
}

// ================= fallback kernels (round-5 verbatim path) =================

__global__ __launch_bounds__(256) void prep_kernel(
    const float* __restrict__ v_w, const float* __restrict__ q_w,
    const float* __restrict__ wih, const float* __restrict__ whh,
    const float* __restrict__ w1, const float* __restrict__ w2,
    float* __restrict__ vwT, float* __restrict__ qwT,
    float* __restrict__ wihT, float* __restrict__ whhT,
    float* __restrict__ w1T, float* __restrict__ w2T)
{
    int i0 = blockIdx.x * blockDim.x + threadIdx.x;
    int nthr = gridDim.x * blockDim.x;
    for (int t = i0; t < 4096; t += nthr) {
        int i = t >> 6, o = t & 63;
        vwT[t] = v_w[o * 64 + i];
        qwT[t] = q_w[o * 64 + i];
    }
    for (int t = i0; t < 12288; t += nthr) {
        int r = t / 192, c = t % 192;
        wihT[t] = wih[c * 64 + r];
        whhT[t] = whh[c * 64 + r];
    }
    for (int t = i0; t < 8192; t += nthr) {
        int r = t >> 7, c = t & 127;
        w1T[t] = w1[c * 64 + r];
    }
    for (int t = i0; t < 8192; t += nthr) {
        int r = t >> 6, c = t & 63;
        w2T[t] = w2[c * 128 + r];
    }
}

__global__ __launch_bounds__(256) void init_q_kernel(
    const float* __restrict__ eps, const float* __restrict__ mu,
    const float* __restrict__ lv, const float* __restrict__ qwT,
    const float* __restrict__ k_w,
    const float* __restrict__ nsw, const float* __restrict__ nsb,
    float* __restrict__ slots, unsigned short* __restrict__ qb,
    float* __restrict__ zbuf)
{
    const int tid = threadIdx.x, lane = tid & 63;
    const int row = blockIdx.x * 4 + (tid >> 6);
    const int idx = row * 64 + lane;
    float s0 = mu[lane] + __expf(0.5f * lv[lane]) * eps[idx];
    slots[idx] = s0;
    float m = warp_red_sum(s0) * (1.0f / 64.0f);
    float dx = s0 - m;
    float var = warp_red_sum(dx * dx) * (1.0f / 64.0f);
    float xln = dx * rsqrtf(var + 1e-5f) * nsw[lane] + nsb[lane];
    float q = 0.f;
    #pragma unroll 8
    for (int i = 0; i < 64; ++i) q = fmaf(bcastlane(xln, i), qwT[i * 64 + lane], q);
    float qp = 0.f;
    #pragma unroll 8
    for (int o = 0; o < 64; ++o) qp = fmaf(bcastlane(q, o), k_w[o * 64 + lane], qp);
    qb[idx] = bfu(qp * 0.125f);
    int g = blockIdx.x * 256 + tid;
    for (int j = g; j < 66560; j += 65536) zbuf[j] = 0.f;
}

__global__ __launch_bounds__(256) void phase_a_ln(
    const float* __restrict__ inp, const float* __restrict__ niw, const float* __restrict__ nib,
    unsigned short* __restrict__ xb)
{
    ln_block(inp, niw, nib, xb, blockIdx.x * 128, threadIdx.x);
}

__global__ __launch_bounds__(256) void attn_mfma(
    const __hip_bfloat16* __restrict__ xb,
    const unsigned short* __restrict__ qb,
    float* __restrict__ numer, float* __restrict__ denom, float* __restrict__ wout)
{
    __shared__ unsigned short smem[11904];
    unsigned short* Qs = smem;
    const int tid = threadIdx.x, lane = tid & 63, widx = tid >> 6;
    unsigned short* wls = smem + 1152 + widx * 640;
    unsigned short* Xw  = smem + 3712 + widx * 2048;
    const int b = blockIdx.y;
    const int quad = lane >> 4, l16 = lane & 15;
    const int twave0 = blockIdx.x * 512 + widx * 128;

    short8 bkA[2][2], bkB[2][2];
    #pragma unroll
    for (int t4h = 0; t4h < 2; ++t4h) {
        const size_t xrow = ((size_t)b * NN + twave0 + t4h * 16 + l16) * 64;
        bkA[t4h][0] = *(const short8*)&xb[xrow + quad * 8];
        bkA[t4h][1] = *(const short8*)&xb[xrow + 32 + quad * 8];
    }

    for (int t = tid; t < 1024; t += 256) {
        int s = t >> 6, dd = t & 63;
        Qs[s * 72 + dd] = (s < 8) ? qb[b * 512 + t] : (unsigned short)0;
    }
    for (int t = lane; t < 320; t += 64) wls[320 + t] = 0;
    __syncthreads();

    short8 aq0 = *(const short8*)&Qs[l16 * 72 + quad * 8];
    short8 aq1 = *(const short8*)&Qs[l16 * 72 + 32 + quad * 8];

    f32x4 accv[4];
    #pragma unroll
    for (int nt = 0; nt < 4; ++nt) accv[nt] = (f32x4){0.f, 0.f, 0.f, 0.f};
    float dacc[4] = {0.f, 0.f, 0.f, 0.f};

    unsigned short* xw0 = Xw + (quad >> 1) * 512 + l16 * 16 + (quad & 1) * 8;
    const unsigned xtr = (unsigned)(size_t)Xw
                       + (unsigned)((quad * 8 + (l16 >> 2)) * 32 + (l16 & 3) * 8);

    auto PROC = [&](short8 (&cur)[2][2], short8 (&nxt)[2][2], int hg, bool pf) {
        const int t0g = twave0 + hg * 32;
        if (pf) {
            #pragma unroll
            for (int t4h = 0; t4h < 2; ++t4h) {
                const size_t xrow = ((size_t)b * NN + t0g + 32 + t4h * 16 + l16) * 64;
                nxt[t4h][0] = *(const short8*)&xb[xrow + quad * 8];
                nxt[t4h][1] = *(const short8*)&xb[xrow + 32 + quad * 8];
            }
        }
        #pragma unroll
        for (int t4h = 0; t4h < 2; ++t4h) {
            const int tok = t0g + t4h * 16 + l16;
            short8 bk0 = cur[t4h][0];
            short8 bk1 = cur[t4h][1];
            *(short8*)(xw0 + t4h * 256) = bk0;
            *(short8*)(xw0 + t4h * 256 + 1024) = bk1;
            f32x4 lg = (f32x4){0.f, 0.f, 0.f, 0.f};
            lg = __builtin_amdgcn_mfma_f32_16x16x32_bf16(aq0, bk0, lg, 0, 0, 0);
            lg = __builtin_amdgcn_mfma_f32_16x16x32_bf16(aq1, bk1, lg, 0, 0, 0);
            float e[4];
            #pragma unroll
            for (int r = 0; r < 4; ++r) e[r] = __expf(lg[r]);
            float s4 = (e[0] + e[1]) + (e[2] + e[3]);
            float stot = s4 + __shfl_xor(s4, 16);
            float rs = __builtin_amdgcn_rcpf(stot);
            float wv[4];
            #pragma unroll
            for (int r = 0; r < 4; ++r) { wv[r] = fmaf(e[r], rs, 1e-8f); dacc[r] += wv[r]; }
            if (quad < 2) {
                #pragma unroll
                for (int r = 0; r < 4; ++r)
                    wls[(quad * 4 + r) * 40 + t4h * 16 + l16] = bfu(wv[r]);
                if (wout)
                    *(float4*)&wout[((size_t)b * NN + tok) * 8 + quad * 4] =
                        make_float4(wv[0], wv[1], wv[2], wv[3]);
            }
        }
        asm volatile("" ::: "memory");
        short8 aw = *(const short8*)&wls[l16 * 40 + quad * 8];
        short4v rlo[4], rhi[4];
        #pragma unroll
        for (int nt = 0; nt < 4; ++nt) {
            rlo[nt] = ds_tr16(xtr + nt * 1024);
            rhi[nt] = ds_tr16(xtr + nt * 1024 + 128);
        }
        asm volatile("s_waitcnt lgkmcnt(0)");
        __builtin_amdgcn_sched_barrier(0);
        #pragma unroll
        for (int nt = 0; nt < 4; ++nt) {
            short8 bv = __builtin_shufflevector(rlo[nt], rhi[nt], 0, 1, 2, 3, 4, 5, 6, 7);
            accv[nt] = __builtin_amdgcn_mfma_f32_16x16x32_bf16(aw, bv, accv[nt], 0, 0, 0);
        }
    };

    PROC(bkA, bkB, 0, true);
    PROC(bkB, bkA, 1, true);
    PROC(bkA, bkB, 2, true);
    PROC(bkB, bkA, 3, false);

    #pragma unroll
    for (int r = 0; r < 4; ++r) {
        dacc[r] += __shfl_xor(dacc[r], 1);
        dacc[r] += __shfl_xor(dacc[r], 2);
        dacc[r] += __shfl_xor(dacc[r], 4);
        dacc[r] += __shfl_xor(dacc[r], 8);
    }
    __syncthreads();
    float* red = (float*)smem;
    float* dred = red + 2048;
    if (quad < 2) {
        #pragma unroll
        for (int nt = 0; nt < 4; ++nt)
            #pragma unroll
            for (int r = 0; r < 4; ++r)
                red[widx * 512 + (quad * 4 + r) * 64 + nt * 16 + l16] = accv[nt][r];
        if (l16 == 0) {
            #pragma unroll
            for (int r = 0; r < 4; ++r) dred[widx * 8 + quad * 4 + r] = dacc[r];
        }
    }
    __syncthreads();
    for (int e = tid; e < 512; e += 256)
        atomicAdd(numer + (size_t)b * 512 + e, red[e] + red[512 + e] + red[1024 + e] + red[1536 + e]);
    if (tid < 8)
        atomicAdd(denom + b * 8 + tid, dred[tid] + dred[8 + tid] + dred[16 + tid] + dred[24 + tid]);
}

__global__ __launch_bounds__(256) void gru_q_kernel(
    const float* __restrict__ numerX, const float* __restrict__ denom,
    const float* __restrict__ slotsIn,
    const float* __restrict__ vwT, const float* __restrict__ wihT, const float* __restrict__ whhT,
    const float* __restrict__ w1T, const float* __restrict__ w2T,
    const float* __restrict__ bih, const float* __restrict__ bhh,
    const float* __restrict__ nrw, const float* __restrict__ nrb,
    const float* __restrict__ b2,
    const float* __restrict__ qwT, const float* __restrict__ k_w,
    const float* __restrict__ nsw, const float* __restrict__ nsb,
    float* __restrict__ slotsOut, unsigned short* __restrict__ qb,
    float* __restrict__ zbuf)
{
    const int tid = threadIdx.x, lane = tid & 63;
    const int row = blockIdx.x * 4 + (tid >> 6);
    float nx = numerX[row * 64 + lane];
    float dt = denom[row];
    gru_core(nx, dt, row, lane, vwT, wihT, whhT, w1T, w2T, bih, bhh, nrw, nrb, b2,
             qwT, k_w, nsw, nsb, slotsIn, slotsOut, qb);
    int g = blockIdx.x * 256 + tid;
    for (int j = g; j < 66560; j += 65536) zbuf[j] = 0.f;
}

__global__ __launch_bounds__(256) void renorm_kernel(float* __restrict__ wout,
                                                     const float* __restrict__ denom)
{
    const size_t i4 = (size_t)blockIdx.x * blockDim.x + threadIdx.x;
    const size_t b = i4 >> 13;
    const int half = (int)(i4 & 1);
    float4 v = reinterpret_cast<float4*>(wout)[i4];
    const float4 dv = reinterpret_cast<const float4*>(denom)[b * 2 + half];
    v.x /= dv.x; v.y /= dv.y; v.z /= dv.z; v.w /= dv.w;
    reinterpret_cast<float4*>(wout)[i4] = v;
}

// ================= host launch =================

extern "C" void kernel_launch(void* const* d_in, const int* in_sizes, int n_in,
                              void* d_out, int out_size, void* d_ws, size_t ws_size,
                              hipStream_t stream)
{
    const float* inputs  = (const float*)d_in[0];
    const float* eps_n   = (const float*)d_in[1];
    const float* mu      = (const float*)d_in[2];
    const float* lv      = (const float*)d_in[3];
    const float* k_w     = (const float*)d_in[4];
    const float* v_w     = (const float*)d_in[5];
    const float* q_w     = (const float*)d_in[6];
    const float* ni_w    = (const float*)d_in[7];
    const float* ni_b    = (const float*)d_in[8];
    const float* ns_w    = (const float*)d_in[9];
    const float* ns_b    = (const float*)d_in[10];
    const float* nr_w    = (const float*)d_in[11];
    const float* nr_b    = (const float*)d_in[12];
    const float* gru_wih = (const float*)d_in[13];
    const float* gru_whh = (const float*)d_in[14];
    const float* gru_bih = (const float*)d_in[15];
    const float* gru_bhh = (const float*)d_in[16];
    const float* mlp_w1  = (const float*)d_in[17];
    const float* mlp_w2  = (const float*)d_in[18];
    const float* mlp_b2  = (const float*)d_in[19];

    char* wsb = (char*)d_ws;
    unsigned short* xb  = (unsigned short*)wsb;          // [B][N][64] bf16
    float* P      = (float*)(wsb + 67108864);
    float* numerP = P;                                   // 524288 floats (B*8 partials x 512)
    float* denomP = P + 524288;                          // 8192
    float* denomF = P + 532480;                          // 1024
    float* f      = (float*)(wsb + 134217728);
    float* slotsA = f;                                   // 65536
    float* slotsB = f + 65536;                           // 65536
    unsigned short* qb = (unsigned short*)(f + 131072);  // 65536 bf16
    float* numer0 = f + 163840;                          // fallback: 65536
    float* denom0 = f + 229376;                          // fallback: 1024
    float* numer1 = f + 230400;                          // fallback: 65536
    float* denom1 = f + 295936;                          // fallback: 1024
    float* vwT    = f + 296960;
    float* qwT    = f + 301056;
    float* wihT   = f + 305152;
    float* whhT   = f + 317440;
    float* w1T    = f + 329728;
    float* w2T    = f + 337920;

    float* out_slots = (float*)d_out;
    float* out_w     = out_slots + 65536;

    MegaArgs a;
    a.inputs = inputs; a.eps = eps_n; a.mu = mu; a.lv = lv;
    a.k_w = k_w; a.v_w = v_w; a.q_w = q_w;
    a.niw = ni_w; a.nib = ni_b; a.nsw = ns_w; a.nsb = ns_b;
    a.nrw = nr_w; a.nrb = nr_b;
    a.wih = gru_wih; a.whh = gru_whh; a.bih = gru_bih; a.bhh = gru_bhh;
    a.w1 = mlp_w1; a.w2 = mlp_w2; a.b2 = mlp_b2;
    a.xb = xb; a.qb = qb;
    a.slotsA = slotsA; a.slotsB = slotsB;
    a.numerP = numerP; a.denomP = denomP; a.denomF = denomF;
    a.vwT = vwT; a.qwT = qwT; a.wihT = wihT; a.whhT = whhT;
    a.w1T = w1T; a.w2T = w2T;
    a.out_slots = out_slots; a.out_w = out_w;

    void* kp[] = { &a };
    hipError_t err = hipLaunchCooperativeKernel((const void*)mega_kernel,
                                                dim3(1024), dim3(256), kp, 0, stream);
    if (err == hipSuccess) return;

    // -------- fallback: round-5 verified multi-kernel path --------
    prep_kernel<<<64, 256, 0, stream>>>(v_w, q_w, gru_wih, gru_whh, mlp_w1, mlp_w2,
                                        vwT, qwT, wihT, whhT, w1T, w2T);
    init_q_kernel<<<256, 256, 0, stream>>>(eps_n, mu, lv, qwT, k_w, ns_w, ns_b,
                                           slotsA, qb, numer0);
    phase_a_ln<<<4096, 256, 0, stream>>>(inputs, ni_w, ni_b, xb);

    float* cur = slotsA;
    float* numers[2] = {numer0, numer1};
    float* denoms[2] = {denom0, denom1};
    for (int step = 0; step < 4; ++step) {
        int pb = step & 1;
        attn_mfma<<<dim3(8, 128), 256, 0, stream>>>((const __hip_bfloat16*)xb, qb,
                                                    numers[pb], denoms[pb],
                                                    step == 3 ? out_w : nullptr);
        float* nxt = (step == 3) ? out_slots : ((step & 1) ? slotsA : slotsB);
        gru_q_kernel<<<256, 256, 0, stream>>>(numers[pb], denoms[pb], cur,
                                              vwT, wihT, whhT, w1T, w2T,
                                              gru_bih, gru_bhh, nr_w, nr_b, mlp_b2,
                                              qwT, k_w, ns_w, ns_b,
                                              nxt, qb, numers[1 - pb]);
        cur = nxt;
    }
    renorm_kernel<<<4096, 256, 0, stream>>>(out_w, denom1);
}

// Round 7
// 378.783 us; speedup vs baseline: 6.2911x; 6.2911x over previous
//
#include <hip/hip_runtime.h>
#include <hip/hip_bf16.h>

#define BB 128
#define NN 4096
#define DD 64
#define SS 8
#define HH 128

typedef __attribute__((ext_vector_type(8))) short short8;
typedef __attribute__((ext_vector_type(4))) short short4v;
typedef __attribute__((ext_vector_type(4))) float f32x4;

__device__ __forceinline__ float warp_red_sum(float v) {
    #pragma unroll
    for (int off = 32; off; off >>= 1) v += __shfl_xor(v, off);
    return v;
}

__device__ __forceinline__ float bcastlane(float v, int l) {
    return __int_as_float(__builtin_amdgcn_readlane(__float_as_int(v), l));
}

__device__ __forceinline__ unsigned short bfu(float f) {
    __hip_bfloat16 h = __float2bfloat16(f);
    return *(unsigned short*)&h;
}

__device__ __forceinline__ unsigned pk2(float a, float b) {
    return (unsigned)bfu(a) | ((unsigned)bfu(b) << 16);
}

// hardware transpose read, CONTRIBUTE semantics (verified vs learn_hip m162):
// within a 16-lane group, lane k's 8 bytes at its own address supply row-major
// elements [4k,4k+4) of a 4x16 bf16 matrix; receiver lane l gets column (l&15).
__device__ __forceinline__ short4v ds_tr16(unsigned off) {
    short4v r;
    asm volatile("ds_read_b64_tr_b16 %0, %1" : "=v"(r) : "v"(off));
    return r;
}

// streaming LN of 128 tokens starting at tok0 (256 threads)
__device__ __forceinline__ void ln_block(
    const float* __restrict__ inp, const float* __restrict__ niw,
    const float* __restrict__ nib, unsigned short* __restrict__ xb,
    int tok0, int tid)
{
    const int lane = tid & 63, widx = tid >> 6;
    const int t8 = lane >> 3, d8 = lane & 7;
    const float4 wn0 = *(const float4*)&niw[d8 * 8];
    const float4 wn1 = *(const float4*)&niw[d8 * 8 + 4];
    const float4 bn0 = *(const float4*)&nib[d8 * 8];
    const float4 bn1 = *(const float4*)&nib[d8 * 8 + 4];
    #pragma unroll
    for (int it = 0; it < 4; ++it) {
        const int m = widx * 32 + it * 8 + t8;
        const float* rowp = inp + (size_t)(tok0 + m) * 64 + d8 * 8;
        float4 a = *(const float4*)rowp;
        float4 c = *(const float4*)(rowp + 4);
        float s1 = (a.x + a.y + a.z + a.w) + (c.x + c.y + c.z + c.w);
        float s2 = fmaf(a.x, a.x, fmaf(a.y, a.y, fmaf(a.z, a.z, a.w * a.w)));
        s2 = fmaf(c.x, c.x, fmaf(c.y, c.y, fmaf(c.z, c.z, fmaf(c.w, c.w, s2))));
        #pragma unroll
        for (int o = 1; o < 8; o <<= 1) { s1 += __shfl_xor(s1, o); s2 += __shfl_xor(s2, o); }
        float mean = s1 * (1.0f / 64.0f);
        float var = s2 * (1.0f / 64.0f) - mean * mean;
        float rstd = rsqrtf(var + 1e-5f);
        float y[8];
        y[0] = (a.x - mean) * rstd * wn0.x + bn0.x;
        y[1] = (a.y - mean) * rstd * wn0.y + bn0.y;
        y[2] = (a.z - mean) * rstd * wn0.z + bn0.z;
        y[3] = (a.w - mean) * rstd * wn0.w + bn0.w;
        y[4] = (c.x - mean) * rstd * wn1.x + bn1.x;
        y[5] = (c.y - mean) * rstd * wn1.y + bn1.y;
        y[6] = (c.z - mean) * rstd * wn1.z + bn1.z;
        y[7] = (c.w - mean) * rstd * wn1.w + bn1.w;
        uint4 o4;
        o4.x = pk2(y[0], y[1]); o4.y = pk2(y[2], y[3]);
        o4.z = pk2(y[4], y[5]); o4.w = pk2(y[6], y[7]);
        *(uint4*)&xb[(size_t)(tok0 + m) * 64 + d8 * 8] = o4;
    }
}

// GRU + MLP + next-q' for one row (64 lanes)
__device__ __forceinline__ void gru_core(
    float nx, float dt, int row, int lane,
    const float* __restrict__ vwT, const float* __restrict__ wihT,
    const float* __restrict__ whhT, const float* __restrict__ w1T,
    const float* __restrict__ w2T, const float* __restrict__ bih,
    const float* __restrict__ bhh, const float* __restrict__ nrw,
    const float* __restrict__ nrb, const float* __restrict__ b2,
    const float* __restrict__ qwT, const float* __restrict__ k_w,
    const float* __restrict__ nsw, const float* __restrict__ nsb,
    const float* __restrict__ slotsIn, float* __restrict__ slotsOut,
    unsigned short* __restrict__ qb)
{
    float xp = 0.f;
    #pragma unroll 8
    for (int i = 0; i < 64; ++i) xp = fmaf(bcastlane(nx, i), vwT[i * 64 + lane], xp);
    float x = xp / dt;
    float h = slotsIn[row * 64 + lane];
    float air = 0, aiz = 0, ain = 0, ahr = 0, ahz = 0, ahn = 0;
    #pragma unroll 8
    for (int i = 0; i < 64; ++i) {
        float xi = bcastlane(x, i), hi = bcastlane(h, i);
        const float* wi = wihT + i * 192;
        const float* wh = whhT + i * 192;
        air = fmaf(xi, wi[lane], air);
        aiz = fmaf(xi, wi[64 + lane], aiz);
        ain = fmaf(xi, wi[128 + lane], ain);
        ahr = fmaf(hi, wh[lane], ahr);
        ahz = fmaf(hi, wh[64 + lane], ahz);
        ahn = fmaf(hi, wh[128 + lane], ahn);
    }
    air += bih[lane]; aiz += bih[64 + lane]; ain += bih[128 + lane];
    ahr += bhh[lane]; ahz += bhh[64 + lane]; ahn += bhh[128 + lane];
    float r = 1.f / (1.f + __expf(-(air + ahr)));
    float z = 1.f / (1.f + __expf(-(aiz + ahz)));
    float n = tanhf(ain + r * ahn);
    float hn = (1.f - z) * n + z * h;
    float m = warp_red_sum(hn) * (1.0f / 64.0f);
    float dx = hn - m;
    float var = warp_red_sum(dx * dx) * (1.0f / 64.0f);
    float u = dx * rsqrtf(var + 1e-5f) * nrw[lane] + nrb[lane];
    float o0 = 0.f, o1 = 0.f;
    #pragma unroll 8
    for (int i = 0; i < 64; ++i) {
        float ui = bcastlane(u, i);
        const float* w1r = w1T + i * 128;
        o0 = fmaf(ui, w1r[lane], o0);
        o1 = fmaf(ui, w1r[64 + lane], o1);
    }
    o0 = fmaxf(o0, 0.f); o1 = fmaxf(o1, 0.f);
    float y = 0.f;
    #pragma unroll 8
    for (int j = 0; j < 64; ++j) y = fmaf(bcastlane(o0, j), w2T[j * 64 + lane], y);
    #pragma unroll 8
    for (int j = 0; j < 64; ++j) y = fmaf(bcastlane(o1, j), w2T[(64 + j) * 64 + lane], y);
    y += b2[lane];
    float out = hn + y;
    slotsOut[row * 64 + lane] = out;
    float m2 = warp_red_sum(out) * (1.0f / 64.0f);
    float dx2 = out - m2;
    float var2 = warp_red_sum(dx2 * dx2) * (1.0f / 64.0f);
    float u2 = dx2 * rsqrtf(var2 + 1e-5f) * nsw[lane] + nsb[lane];
    float q = 0.f;
    #pragma unroll 8
    for (int i = 0; i < 64; ++i) q = fmaf(bcastlane(u2, i), qwT[i * 64 + lane], q);
    float qp = 0.f;
    #pragma unroll 8
    for (int o = 0; o < 64; ++o) qp = fmaf(bcastlane(q, o), k_w[o * 64 + lane], qp);
    qb[row * 64 + lane] = bfu(qp * 0.125f);
}

// ---------------- fused pre-pass: LN (all blocks) + prep (blocks 0..63) +
// slot-init/q' (blocks 64..319, one row per wave; direct q_w/k_w reads) ----------------
__global__ __launch_bounds__(256) void fused_pre(
    const float* __restrict__ inp, const float* __restrict__ niw, const float* __restrict__ nib,
    const float* __restrict__ eps, const float* __restrict__ mu, const float* __restrict__ lv,
    const float* __restrict__ q_w, const float* __restrict__ k_w,
    const float* __restrict__ nsw, const float* __restrict__ nsb,
    const float* __restrict__ v_w, const float* __restrict__ wih, const float* __restrict__ whh,
    const float* __restrict__ w1, const float* __restrict__ w2,
    unsigned short* __restrict__ xb, unsigned short* __restrict__ qb,
    float* __restrict__ slots,
    float* __restrict__ vwT, float* __restrict__ qwT,
    float* __restrict__ wihT, float* __restrict__ whhT,
    float* __restrict__ w1T, float* __restrict__ w2T)
{
    const int bid = blockIdx.x, tid = threadIdx.x;
    const int lane = tid & 63, widx = tid >> 6;
    if (bid < 64) {
        int i0 = bid * 256 + tid, nthr = 16384;
        for (int t = i0; t < 4096; t += nthr) {
            int i = t >> 6, o = t & 63;
            vwT[t] = v_w[o * 64 + i];
            qwT[t] = q_w[o * 64 + i];
        }
        for (int t = i0; t < 12288; t += nthr) {
            int r = t / 192, c = t % 192;
            wihT[t] = wih[c * 64 + r];
            whhT[t] = whh[c * 64 + r];
        }
        for (int t = i0; t < 8192; t += nthr) {
            int r = t >> 7, c = t & 127;
            w1T[t] = w1[c * 64 + r];
        }
        for (int t = i0; t < 8192; t += nthr) {
            int r = t >> 6, c = t & 63;
            w2T[t] = w2[c * 128 + r];
        }
    }
    ln_block(inp, niw, nib, xb, bid * 128, tid);
    if (bid >= 64 && bid < 320) {
        const int row = (bid - 64) * 4 + widx;
        const int idx = row * 64 + lane;
        float s0 = mu[lane] + __expf(0.5f * lv[lane]) * eps[idx];
        slots[idx] = s0;
        float m = warp_red_sum(s0) * (1.0f / 64.0f);
        float dx = s0 - m;
        float var = warp_red_sum(dx * dx) * (1.0f / 64.0f);
        float xln = dx * rsqrtf(var + 1e-5f) * nsw[lane] + nsb[lane];
        float q = 0.f;
        #pragma unroll 8
        for (int i = 0; i < 64; ++i) q = fmaf(bcastlane(xln, i), q_w[lane * 64 + i], q);
        float qp = 0.f;
        #pragma unroll 8
        for (int o = 0; o < 64; ++o) qp = fmaf(bcastlane(q, o), k_w[o * 64 + lane], qp);
        qb[idx] = bfu(qp * 0.125f);
    }
}

// ---------------- attention via MFMA: q'·X^T -> softmax -> w^T·X partials ----------------
// QK: A=q', B=X rows from global (rolling 32-token prefetch, group0 pre-barrier).
// Staging: lane's short8 -> subtiled per-wave LDS tile Xw[4][32][16] (one ds_write_b128).
// PV B-frags: ds_read_b64_tr_b16 (contribute addressing, verified r5).
// Epilogue: per-(b,xblk) PLAIN partial stores — NO device atomics (round-6 theory:
// 524K cross-XCD f32 atomicAdds were ~50 us/dispatch; partials + gru-side reduce).
__global__ __launch_bounds__(256) void attn_mfma(
    const __hip_bfloat16* __restrict__ xb,
    const unsigned short* __restrict__ qb,
    float* __restrict__ numerP, float* __restrict__ denomP, float* __restrict__ wout)
{
    __shared__ unsigned short smem[11904];
    unsigned short* Qs = smem;                          // [16][72]
    const int tid = threadIdx.x, lane = tid & 63, widx = tid >> 6;
    unsigned short* wls = smem + 1152 + widx * 640;     // [16][40] per wave
    unsigned short* Xw  = smem + 3712 + widx * 2048;    // [4][32][16] per wave
    const int b = blockIdx.y;
    const int quad = lane >> 4, l16 = lane & 15;
    const int twave0 = blockIdx.x * 512 + widx * 128;

    short8 bkA[2][2], bkB[2][2];
    #pragma unroll
    for (int t4h = 0; t4h < 2; ++t4h) {
        const size_t xrow = ((size_t)b * NN + twave0 + t4h * 16 + l16) * 64;
        bkA[t4h][0] = *(const short8*)&xb[xrow + quad * 8];
        bkA[t4h][1] = *(const short8*)&xb[xrow + 32 + quad * 8];
    }

    for (int t = tid; t < 1024; t += 256) {
        int s = t >> 6, dd = t & 63;
        Qs[s * 72 + dd] = (s < 8) ? qb[b * 512 + t] : (unsigned short)0;
    }
    for (int t = lane; t < 320; t += 64) wls[320 + t] = 0;
    __syncthreads();

    short8 aq0 = *(const short8*)&Qs[l16 * 72 + quad * 8];
    short8 aq1 = *(const short8*)&Qs[l16 * 72 + 32 + quad * 8];

    f32x4 accv[4];
    #pragma unroll
    for (int nt = 0; nt < 4; ++nt) accv[nt] = (f32x4){0.f, 0.f, 0.f, 0.f};
    float dacc[4] = {0.f, 0.f, 0.f, 0.f};

    unsigned short* xw0 = Xw + (quad >> 1) * 512 + l16 * 16 + (quad & 1) * 8;
    const unsigned xtr = (unsigned)(size_t)Xw
                       + (unsigned)((quad * 8 + (l16 >> 2)) * 32 + (l16 & 3) * 8);

    auto PROC = [&](short8 (&cur)[2][2], short8 (&nxt)[2][2], int hg, bool pf) {
        const int t0g = twave0 + hg * 32;
        if (pf) {
            #pragma unroll
            for (int t4h = 0; t4h < 2; ++t4h) {
                const size_t xrow = ((size_t)b * NN + t0g + 32 + t4h * 16 + l16) * 64;
                nxt[t4h][0] = *(const short8*)&xb[xrow + quad * 8];
                nxt[t4h][1] = *(const short8*)&xb[xrow + 32 + quad * 8];
            }
        }
        #pragma unroll
        for (int t4h = 0; t4h < 2; ++t4h) {
            const int tok = t0g + t4h * 16 + l16;
            short8 bk0 = cur[t4h][0];
            short8 bk1 = cur[t4h][1];
            *(short8*)(xw0 + t4h * 256) = bk0;
            *(short8*)(xw0 + t4h * 256 + 1024) = bk1;
            f32x4 lg = (f32x4){0.f, 0.f, 0.f, 0.f};
            lg = __builtin_amdgcn_mfma_f32_16x16x32_bf16(aq0, bk0, lg, 0, 0, 0);
            lg = __builtin_amdgcn_mfma_f32_16x16x32_bf16(aq1, bk1, lg, 0, 0, 0);
            float e[4];
            #pragma unroll
            for (int r = 0; r < 4; ++r) e[r] = __expf(lg[r]);
            float s4 = (e[0] + e[1]) + (e[2] + e[3]);
            float stot = s4 + __shfl_xor(s4, 16);
            float rs = __builtin_amdgcn_rcpf(stot);
            float wv[4];
            #pragma unroll
            for (int r = 0; r < 4; ++r) { wv[r] = fmaf(e[r], rs, 1e-8f); dacc[r] += wv[r]; }
            if (quad < 2) {
                #pragma unroll
                for (int r = 0; r < 4; ++r)
                    wls[(quad * 4 + r) * 40 + t4h * 16 + l16] = bfu(wv[r]);
                if (wout)
                    *(float4*)&wout[((size_t)b * NN + tok) * 8 + quad * 4] =
                        make_float4(wv[0], wv[1], wv[2], wv[3]);
            }
        }
        asm volatile("" ::: "memory");
        short8 aw = *(const short8*)&wls[l16 * 40 + quad * 8];
        short4v rlo[4], rhi[4];
        #pragma unroll
        for (int nt = 0; nt < 4; ++nt) {
            rlo[nt] = ds_tr16(xtr + nt * 1024);
            rhi[nt] = ds_tr16(xtr + nt * 1024 + 128);
        }
        asm volatile("s_waitcnt lgkmcnt(0)");
        __builtin_amdgcn_sched_barrier(0);
        #pragma unroll
        for (int nt = 0; nt < 4; ++nt) {
            short8 bv = __builtin_shufflevector(rlo[nt], rhi[nt], 0, 1, 2, 3, 4, 5, 6, 7);
            accv[nt] = __builtin_amdgcn_mfma_f32_16x16x32_bf16(aw, bv, accv[nt], 0, 0, 0);
        }
    };

    PROC(bkA, bkB, 0, true);
    PROC(bkB, bkA, 1, true);
    PROC(bkA, bkB, 2, true);
    PROC(bkB, bkA, 3, false);

    #pragma unroll
    for (int r = 0; r < 4; ++r) {
        dacc[r] += __shfl_xor(dacc[r], 1);
        dacc[r] += __shfl_xor(dacc[r], 2);
        dacc[r] += __shfl_xor(dacc[r], 4);
        dacc[r] += __shfl_xor(dacc[r], 8);
    }
    __syncthreads();
    float* red = (float*)smem;
    float* dred = red + 2048;
    if (quad < 2) {
        #pragma unroll
        for (int nt = 0; nt < 4; ++nt)
            #pragma unroll
            for (int r = 0; r < 4; ++r)
                red[widx * 512 + (quad * 4 + r) * 64 + nt * 16 + l16] = accv[nt][r];
        if (l16 == 0) {
            #pragma unroll
            for (int r = 0; r < 4; ++r) dred[widx * 8 + quad * 4 + r] = dacc[r];
        }
    }
    __syncthreads();
    float* np = numerP + ((size_t)b * 8 + blockIdx.x) * 512;
    for (int e = tid; e < 512; e += 256)
        np[e] = red[e] + red[512 + e] + red[1024 + e] + red[1536 + e];
    if (tid < 8)
        denomP[((size_t)b * 8 + blockIdx.x) * 8 + tid] =
            dred[tid] + dred[8 + tid] + dred[16 + tid] + dred[24 + tid];
}

// ---------------- GRU + MLP + next q' (reduces the 8 partials) ----------------
__global__ __launch_bounds__(256) void gru_q_kernel(
    const float* __restrict__ numerP, const float* __restrict__ denomP,
    const float* __restrict__ slotsIn,
    const float* __restrict__ vwT, const float* __restrict__ wihT, const float* __restrict__ whhT,
    const float* __restrict__ w1T, const float* __restrict__ w2T,
    const float* __restrict__ bih, const float* __restrict__ bhh,
    const float* __restrict__ nrw, const float* __restrict__ nrb,
    const float* __restrict__ b2,
    const float* __restrict__ qwT, const float* __restrict__ k_w,
    const float* __restrict__ nsw, const float* __restrict__ nsb,
    float* __restrict__ slotsOut, unsigned short* __restrict__ qb,
    float* __restrict__ denomF)
{
    const int tid = threadIdx.x, lane = tid & 63;
    const int row = blockIdx.x * 4 + (tid >> 6);
    const int bb = row >> 3, ss = row & 7;
    float nx = 0.f, dt = 0.f;
    #pragma unroll
    for (int xx = 0; xx < 8; ++xx) {
        nx += numerP[((size_t)bb * 8 + xx) * 512 + ss * 64 + lane];
        dt += denomP[((size_t)bb * 8 + xx) * 8 + ss];
    }
    if (lane == 0) denomF[row] = dt;
    gru_core(nx, dt, row, lane, vwT, wihT, whhT, w1T, w2T, bih, bhh, nrw, nrb, b2,
             qwT, k_w, nsw, nsb, slotsIn, slotsOut, qb);
}

// ---------------- final renorm of w output ----------------
__global__ __launch_bounds__(256) void renorm_kernel(float* __restrict__ wout,
                                                     const float* __restrict__ denom)
{
    const size_t i4 = (size_t)blockIdx.x * blockDim.x + threadIdx.x;
    const size_t b = i4 >> 13;
    const int half = (int)(i4 & 1);
    float4 v = reinterpret_cast<float4*>(wout)[i4];
    const float4 dv = reinterpret_cast<const float4*>(denom)[b * 2 + half];
    v.x /= dv.x; v.y /= dv.y; v.z /= dv.z; v.w /= dv.w;
    reinterpret_cast<float4*>(wout)[i4] = v;
}

extern "C" void kernel_launch(void* const* d_in, const int* in_sizes, int n_in,
                              void* d_out, int out_size, void* d_ws, size_t ws_size,
                              hipStream_t stream)
{
    const float* inputs  = (const float*)d_in[0];
    const float* eps_n   = (const float*)d_in[1];
    const float* mu      = (const float*)d_in[2];
    const float* lv      = (const float*)d_in[3];
    const float* k_w     = (const float*)d_in[4];
    const float* v_w     = (const float*)d_in[5];
    const float* q_w     = (const float*)d_in[6];
    const float* ni_w    = (const float*)d_in[7];
    const float* ni_b    = (const float*)d_in[8];
    const float* ns_w    = (const float*)d_in[9];
    const float* ns_b    = (const float*)d_in[10];
    const float* nr_w    = (const float*)d_in[11];
    const float* nr_b    = (const float*)d_in[12];
    const float* gru_wih = (const float*)d_in[13];
    const float* gru_whh = (const float*)d_in[14];
    const float* gru_bih = (const float*)d_in[15];
    const float* gru_bhh = (const float*)d_in[16];
    const float* mlp_w1  = (const float*)d_in[17];
    const float* mlp_w2  = (const float*)d_in[18];
    const float* mlp_b2  = (const float*)d_in[19];

    char* wsb = (char*)d_ws;
    unsigned short* xb  = (unsigned short*)wsb;          // [B][N][64] bf16 (LN'd X)
    float* P      = (float*)(wsb + 67108864);
    float* numerP = P;                                   // B*8 partials x 512 = 524288
    float* denomP = P + 524288;                          // B*8 x 8 = 8192
    float* denomF = P + 532480;                          // 1024
    float* f      = (float*)(wsb + 134217728);
    float* slotsA = f;                                   // 65536
    float* slotsB = f + 65536;                           // 65536
    unsigned short* qb = (unsigned short*)(f + 131072);  // 65536 bf16 (q')
    float* vwT    = f + 296960;
    float* qwT    = f + 301056;
    float* wihT   = f + 305152;
    float* whhT   = f + 317440;
    float* w1T    = f + 329728;
    float* w2T    = f + 337920;

    float* out_slots = (float*)d_out;
    float* out_w     = out_slots + 65536;

    fused_pre<<<4096, 256, 0, stream>>>(inputs, ni_w, ni_b, eps_n, mu, lv,
                                        q_w, k_w, ns_w, ns_b,
                                        v_w, gru_wih, gru_whh, mlp_w1, mlp_w2,
                                        xb, qb, slotsA,
                                        vwT, qwT, wihT, whhT, w1T, w2T);

    float* cur = slotsA;
    for (int step = 0; step < 4; ++step) {
        attn_mfma<<<dim3(8, 128), 256, 0, stream>>>((const __hip_bfloat16*)xb, qb,
                                                    numerP, denomP,
                                                    step == 3 ? out_w : nullptr);
        float* nxt = (step == 3) ? out_slots : ((step & 1) ? slotsA : slotsB);
        gru_q_kernel<<<256, 256, 0, stream>>>(numerP, denomP, cur,
                                              vwT, wihT, whhT, w1T, w2T,
                                              gru_bih, gru_bhh, nr_w, nr_b, mlp_b2,
                                              qwT, k_w, ns_w, ns_b,
                                              nxt, qb, denomF);
        cur = nxt;
    }
    renorm_kernel<<<4096, 256, 0, stream>>>(out_w, denomF);
}